// Round 1
// baseline (213.053 us; speedup 1.0000x reference)
//
#include <hip/hip_runtime.h>
#include <hip/hip_bf16.h>

#define NNODES   524288
#define NGRAPHS  4096
#define GS       12    // head LDS row stride (floats)

typedef __attribute__((ext_vector_type(8)))  short short8;
typedef __attribute__((ext_vector_type(4)))  float f32x4;
typedef __attribute__((ext_vector_type(16))) float f32x16;

static __device__ __forceinline__ unsigned short f2bf(float f) {
    __hip_bfloat16 h = __float2bfloat16(f);
    return *reinterpret_cast<unsigned short*>(&h);
}

// swizzled LDS offset (shorts): node-row 128 shorts, 16B chunks XOR-permuted
static __device__ __forceinline__ int swz(int node, int chunk) {
    return node * 128 + ((chunk ^ (node & 15)) << 3);
}

// ---- one-time: bf16 weight transposes. wT[of][k] = w[k][of]; w0p[of][16] K-padded ----
__global__ __launch_bounds__(256) void prep_weights(
        const float* __restrict__ w0, const float* __restrict__ w1,
        const float* __restrict__ w2,
        unsigned short* __restrict__ w0p, unsigned short* __restrict__ w1T,
        unsigned short* __restrict__ w2T) {
    int e = blockIdx.x * 256 + threadIdx.x;
    if (e < 16384) {
        int k = e >> 7, n = e & 127;
        w1T[n * 128 + k] = f2bf(w1[e]);
    } else if (e < 32768) {
        int i = e - 16384;
        int k = i >> 7, n = i & 127;
        w2T[n * 128 + k] = f2bf(w2[i]);
    } else if (e < 34816) {
        int i = e - 32768;                 // w0p[128][16], K=4 zero-padded to 16
        int of = i >> 4, k = i & 15;
        w0p[i] = (k < 4) ? f2bf(w0[k * 128 + of]) : (unsigned short)0;
    }
}

// ---- fused phi MLP: 2 waves/block, of-split (64 of each), 64 nodes/block ----
// acc = 4 tiles (64 AGPR) per wave -> 3 waves/SIMD vs old 2. h exchanged via LDS.
__global__ __launch_bounds__(128, 3) void phi_kernel(
        const float* __restrict__ x, const int* __restrict__ batch,
        const unsigned short* __restrict__ w0p, const float* __restrict__ b0,
        const unsigned short* __restrict__ w1T, const float* __restrict__ b1,
        const unsigned short* __restrict__ w2T, const float* __restrict__ b2,
        float* __restrict__ g) {
    __shared__ __align__(16) unsigned short hb[64 * 128];   // 16384 B, block-shared
    const int tid  = threadIdx.x;
    const int lane = tid & 63;
    const int wv   = tid >> 6;        // wave id = of-half owner
    const int wof  = wv * 64;         // of base for this wave
    const int n0   = blockIdx.x * 64;
    const int l31  = lane & 31;
    const int h    = lane >> 5;

    // graph ids + run-start mask (registers only, per wave — identical in both)
    const int gi = batch[n0 + lane];
    const int gp = __shfl_up(gi, 1);
    const unsigned long long mask = __ballot((lane == 0) || (gi != gp));

    f32x16 acc[4];

    // swapped-C writeback: col=node (lane&31), row=of-local ((reg&3)+8*(reg>>2)+4*h)
    // this wave writes only its own of-half chunks [wof/8, wof/8+8)
    auto writeback = [&](const float* __restrict__ bias) {
        #pragma unroll
        for (int mt = 0; mt < 2; ++mt) {
            #pragma unroll
            for (int g4 = 0; g4 < 4; ++g4) {
                const int of0 = wof + mt*32 + 8*g4 + 4*h;
                const float4 bv = *reinterpret_cast<const float4*>(bias + of0);
                #pragma unroll
                for (int nt = 0; nt < 2; ++nt) {
                    const int node = nt*32 + l31;
                    const f32x16 A = acc[mt*2 + nt];
                    ushort4 s;
                    s.x = f2bf(fmaxf(A[g4*4+0] + bv.x, 0.f));
                    s.y = f2bf(fmaxf(A[g4*4+1] + bv.y, 0.f));
                    s.z = f2bf(fmaxf(A[g4*4+2] + bv.z, 0.f));
                    s.w = f2bf(fmaxf(A[g4*4+3] + bv.w, 0.f));
                    const int chunk = (wof >> 3) + mt*4 + g4;
                    *reinterpret_cast<ushort4*>(&hb[swz(node, chunk) + h*4]) = s;
                }
            }
        }
    };

    // ---- layer 1 (swapped: A = w0p [of][k] for this of-half, B = x rows, K=16) ----
    {
        short8 af[2];
        #pragma unroll
        for (int mt = 0; mt < 2; ++mt)
            af[mt] = *reinterpret_cast<const short8*>(
                w0p + (wof + mt*32 + l31) * 16 + h*8);
        short8 bf[2];
        #pragma unroll
        for (int nt = 0; nt < 2; ++nt) {
            const float4 xv = *reinterpret_cast<const float4*>(
                x + (size_t)(n0 + nt*32 + l31) * 4);
            short8 v = (short8){0,0,0,0,0,0,0,0};
            if (h == 0) {
                v[0] = (short)f2bf(xv.x); v[1] = (short)f2bf(xv.y);
                v[2] = (short)f2bf(xv.z); v[3] = (short)f2bf(xv.w);
            }
            bf[nt] = v;
        }
        #pragma unroll
        for (int t = 0; t < 4; ++t) acc[t] = (f32x16){};
        #pragma unroll
        for (int mt = 0; mt < 2; ++mt)
            #pragma unroll
            for (int nt = 0; nt < 2; ++nt)
                acc[mt*2 + nt] = __builtin_amdgcn_mfma_f32_32x32x16_bf16(
                    af[mt], bf[nt], acc[mt*2 + nt], 0, 0, 0);
    }
    writeback(b0);
    __syncthreads();   // other wave's of-half visible

    // ---- layer 2 (swapped: A = w1T [of][k] of-half, B = hb rows, K=128 full) ----
    #pragma unroll
    for (int t = 0; t < 4; ++t) acc[t] = (f32x16){};
    #pragma unroll
    for (int ks = 0; ks < 8; ++ks) {
        short8 a[2], b[2];
        #pragma unroll
        for (int mt = 0; mt < 2; ++mt)
            a[mt] = *reinterpret_cast<const short8*>(
                w1T + (wof + mt*32 + l31) * 128 + ks*16 + h*8);
        #pragma unroll
        for (int nt = 0; nt < 2; ++nt)
            b[nt] = *reinterpret_cast<const short8*>(&hb[swz(nt*32 + l31, ks*2 + h)]);
        #pragma unroll
        for (int mt = 0; mt < 2; ++mt)
            #pragma unroll
            for (int nt = 0; nt < 2; ++nt)
                acc[mt*2 + nt] = __builtin_amdgcn_mfma_f32_32x32x16_bf16(
                    a[mt], b[nt], acc[mt*2 + nt], 0, 0, 0);
    }
    __syncthreads();   // both waves done READING hb (MFMA operands drained)
    writeback(b1);     // overwrite own of-half
    __syncthreads();   // writes visible

    // ---- layer 3 (normal: A = hb rows [node][k] full K, B = w2T of-half) ----
    #pragma unroll
    for (int t = 0; t < 4; ++t) acc[t] = (f32x16){};
    #pragma unroll
    for (int ks = 0; ks < 8; ++ks) {
        short8 a[2], bb[2];
        #pragma unroll
        for (int mtn = 0; mtn < 2; ++mtn)
            a[mtn] = *reinterpret_cast<const short8*>(&hb[swz(mtn*32 + l31, ks*2 + h)]);
        #pragma unroll
        for (int ntc = 0; ntc < 2; ++ntc)
            bb[ntc] = *reinterpret_cast<const short8*>(
                w2T + (wof + ntc*32 + l31) * 128 + ks*16 + h*8);
        #pragma unroll
        for (int mtn = 0; mtn < 2; ++mtn)
            #pragma unroll
            for (int ntc = 0; ntc < 2; ++ntc)
                acc[mtn*2 + ntc] = __builtin_amdgcn_mfma_f32_32x32x16_bf16(
                    a[mtn], bb[ntc], acc[mtn*2 + ntc], 0, 0, 0);
    }

    // ---- epilogue: register segmented sum. C: col=of-local (l31), row=node ----
    float b2v[2];
    #pragma unroll
    for (int ntc = 0; ntc < 2; ++ntc) b2v[ntc] = b2[wof + ntc*32 + l31];

    unsigned long long rem = mask & (mask - 1);
    int s = 0;
    while (true) {
        const int e = rem ? (int)__builtin_ctzll(rem) : 64;
        const int grun = __shfl(gi, s);
        const float cnt = (float)(e - s);
        float* gdst = g + (size_t)grun * 128 + wof;
        #pragma unroll
        for (int ntc = 0; ntc < 2; ++ntc) {
            float val = 0.f;
            #pragma unroll
            for (int mtn = 0; mtn < 2; ++mtn) {
                const f32x16 A = acc[mtn*2 + ntc];
                #pragma unroll
                for (int r = 0; r < 16; ++r) {
                    const int node = mtn*32 + (r & 3) + 8*(r >> 2) + 4*h;
                    const float inc = (node >= s && node < e) ? 1.f : 0.f;
                    val = fmaf(A[r], inc, val);
                }
            }
            val += __shfl_xor(val, 32);
            if (h == 0)
                atomicAdd(gdst + ntc*32 + l31, fmaf(cnt, b2v[ntc], val));
        }
        if (!rem) break;
        s = e;
        rem &= rem - 1;
    }
}

// ---- F head: fused 3 layers, 4 graphs/block, 1024 blocks (2x occupancy) ----
__global__ __launch_bounds__(256) void head_kernel(
        const float* __restrict__ g,
        const float* __restrict__ fw0, const float* __restrict__ fb0,
        const float* __restrict__ fw1, const float* __restrict__ fb1,
        const float* __restrict__ fw2, const float* __restrict__ fb2,
        float* __restrict__ out) {
    __shared__ float gS[128 * GS];
    __shared__ float h1T[256 * GS];
    __shared__ float red[4][8];
    const int tid = threadIdx.x;
    const int g0  = blockIdx.x * 4;

    {
        const int gr = tid >> 6, k0 = (tid & 63) * 2;
        const float2 v = *reinterpret_cast<const float2*>(
            g + (size_t)(g0 + gr) * 128 + k0);
        gS[(k0+0)*GS + gr] = v.x;
        gS[(k0+1)*GS + gr] = v.y;
    }
    __syncthreads();

    float a1[4];
    #pragma unroll
    for (int i = 0; i < 4; ++i) a1[i] = 0.f;
    #pragma unroll 4
    for (int k = 0; k < 128; ++k) {
        const float w = fw0[k * 256 + tid];
        const f32x4 v0 = *reinterpret_cast<const f32x4*>(&gS[k*GS]);
        #pragma unroll
        for (int j = 0; j < 4; ++j)
            a1[j] = fmaf(v0[j], w, a1[j]);
    }
    {
        const float bb = fb0[tid];
        f32x4 s0;
        #pragma unroll
        for (int j = 0; j < 4; ++j)
            s0[j] = fmaxf(a1[j] + bb, 0.f);
        *reinterpret_cast<f32x4*>(&h1T[tid*GS]) = s0;
    }
    __syncthreads();

    float a2[4];
    #pragma unroll
    for (int i = 0; i < 4; ++i) a2[i] = 0.f;
    #pragma unroll 4
    for (int k = 0; k < 256; ++k) {
        const float w = fw1[k * 256 + tid];
        const f32x4 v0 = *reinterpret_cast<const f32x4*>(&h1T[k*GS]);
        #pragma unroll
        for (int j = 0; j < 4; ++j)
            a2[j] = fmaf(v0[j], w, a2[j]);
    }

    float p[8];
    {
        const float bb  = fb1[tid];
        const float w2a = fw2[tid*2 + 0];
        const float w2b = fw2[tid*2 + 1];
        #pragma unroll
        for (int i = 0; i < 4; ++i) {
            const float h2 = fmaxf(a2[i] + bb, 0.f);
            p[i*2 + 0] = h2 * w2a;
            p[i*2 + 1] = h2 * w2b;
        }
    }
    #pragma unroll
    for (int i = 0; i < 8; ++i) {
        float v = p[i];
        v += __shfl_xor(v, 32); v += __shfl_xor(v, 16); v += __shfl_xor(v, 8);
        v += __shfl_xor(v, 4);  v += __shfl_xor(v, 2);  v += __shfl_xor(v, 1);
        p[i] = v;
    }
    if ((tid & 63) == 0) {
        #pragma unroll
        for (int i = 0; i < 8; ++i) red[tid >> 6][i] = p[i];
    }
    __syncthreads();
    if (tid < 8)
        out[g0*2 + tid] = red[0][tid] + red[1][tid] + red[2][tid] + red[3][tid]
                        + fb2[tid & 1];
}

extern "C" void kernel_launch(void* const* d_in, const int* in_sizes, int n_in,
                              void* d_out, int out_size, void* d_ws, size_t ws_size,
                              hipStream_t stream) {
    const float* x   = (const float*)d_in[0];
    // d_in[1] edge_index: mathematically dead (update() ignores aggr_out) — never read
    const int*   batch = (const int*)d_in[2];
    const float* w0  = (const float*)d_in[3];
    const float* b0  = (const float*)d_in[4];
    const float* w1  = (const float*)d_in[5];
    const float* b1  = (const float*)d_in[6];
    const float* w2  = (const float*)d_in[7];
    const float* b2  = (const float*)d_in[8];
    const float* fw0 = (const float*)d_in[9];
    const float* fb0 = (const float*)d_in[10];
    const float* fw1 = (const float*)d_in[11];
    const float* fb1 = (const float*)d_in[12];
    const float* fw2 = (const float*)d_in[13];
    const float* fb2 = (const float*)d_in[14];
    float* out = (float*)d_out;

    float* g = (float*)d_ws;                                        // 2 MB
    unsigned short* w1T = (unsigned short*)((char*)d_ws + (size_t)NGRAPHS * 128 * 4);
    unsigned short* w2T = w1T + 128 * 128;
    unsigned short* w0p = w2T + 128 * 128;                          // 4 KB

    (void)hipMemsetAsync(g, 0, (size_t)NGRAPHS * 128 * sizeof(float), stream);
    prep_weights<<<136, 256, 0, stream>>>(w0, w1, w2, w0p, w1T, w2T);
    phi_kernel<<<NNODES / 64, 128, 0, stream>>>(x, batch, w0p, b0, w1T, b1, w2T, b2, g);
    head_kernel<<<NGRAPHS / 4, 256, 0, stream>>>(g, fw0, fb0, fw1, fb1, fw2, fb2, out);
}

// Round 2
// 180.679 us; speedup vs baseline: 1.1792x; 1.1792x over previous
//
#include <hip/hip_runtime.h>
#include <hip/hip_bf16.h>

#define NNODES   524288
#define NGRAPHS  4096
#define GS       12    // head LDS row stride (floats)

typedef __attribute__((ext_vector_type(8)))  short short8;
typedef __attribute__((ext_vector_type(4)))  float f32x4;
typedef __attribute__((ext_vector_type(16))) float f32x16;

static __device__ __forceinline__ unsigned short f2bf(float f) {
    __hip_bfloat16 h = __float2bfloat16(f);
    return *reinterpret_cast<unsigned short*>(&h);
}

// swizzled LDS offset (shorts): node-row 128 shorts, 16B chunks XOR-permuted
static __device__ __forceinline__ int swz(int node, int chunk) {
    return node * 128 + ((chunk ^ (node & 15)) << 3);
}

// ---- one-time: weights into bf16 FRAGMENT-MAJOR layout ----
// wF flat index = (((half*8 + ks)*2 + mt)*64 + lane)*8 + j
//   of = half*64 + mt*32 + (lane&31),  k = ks*16 + (lane>>5)*8 + j
// so each wave's fragment load is one contiguous 1KB (64 lanes x 16B).
__global__ __launch_bounds__(256) void prep_weights(
        const float* __restrict__ w0, const float* __restrict__ w1,
        const float* __restrict__ w2,
        unsigned short* __restrict__ w0F, unsigned short* __restrict__ w1F,
        unsigned short* __restrict__ w2F) {
    int e = blockIdx.x * 256 + threadIdx.x;
    if (e < 16384) {
        const int j = e & 7, lane = (e >> 3) & 63, mt = (e >> 9) & 1,
                  ks = (e >> 10) & 7, half = (e >> 13) & 1;
        const int of = half * 64 + mt * 32 + (lane & 31);
        const int k  = ks * 16 + (lane >> 5) * 8 + j;
        w1F[e] = f2bf(w1[k * 128 + of]);
    } else if (e < 32768) {
        const int i = e - 16384;
        const int j = i & 7, lane = (i >> 3) & 63, mt = (i >> 9) & 1,
                  ks = (i >> 10) & 7, half = (i >> 13) & 1;
        const int of = half * 64 + mt * 32 + (lane & 31);
        const int k  = ks * 16 + (lane >> 5) * 8 + j;
        w2F[i] = f2bf(w2[k * 128 + of]);
    } else if (e < 34816) {
        const int i = e - 32768;           // w0F[half][mt][lane][8], K=4 padded to 16
        const int j = i & 7, lane = (i >> 3) & 63, mt = (i >> 9) & 1,
                  half = (i >> 10) & 1;
        const int of = half * 64 + mt * 32 + (lane & 31);
        const int k  = (lane >> 5) * 8 + j;
        w0F[i] = (k < 4) ? f2bf(w0[k * 128 + of]) : (unsigned short)0;
    }
}

// ---- fused phi MLP: 4 waves/block (of-half x node-half), 128 nodes/block ----
// acc = 4 tiles (64 AGPR)/wave; weight loads are 1KB wave-coalesced fragments.
__global__ __launch_bounds__(256, 3) void phi_kernel(
        const float* __restrict__ x, const int* __restrict__ batch,
        const unsigned short* __restrict__ w0F, const float* __restrict__ b0,
        const unsigned short* __restrict__ w1F, const float* __restrict__ b1,
        const unsigned short* __restrict__ w2F, const float* __restrict__ b2,
        float* __restrict__ g) {
    __shared__ __align__(16) unsigned short hb[128 * 128];   // 32 KB
    const int tid  = threadIdx.x;
    const int lane = tid & 63;
    const int wv   = tid >> 6;
    const int half = wv & 1;          // of-half owner
    const int wof  = half * 64;
    const int nb   = (wv >> 1) * 64;  // node-half base (within block)
    const int n0   = blockIdx.x * 128;
    const int l31  = lane & 31;
    const int h    = lane >> 5;

    // graph ids + run-start mask over this wave's 64-node window
    const int gi = batch[n0 + nb + lane];
    const int gp = __shfl_up(gi, 1);
    const unsigned long long mask = __ballot((lane == 0) || (gi != gp));

    f32x16 acc[4];

    // swapped-C writeback: col=node (lane&31), row=of-local ((reg&3)+8*(reg>>2)+4*h)
    // this wave writes its of-half chunks of its node-half rows
    auto writeback = [&](const float* __restrict__ bias) {
        #pragma unroll
        for (int mt = 0; mt < 2; ++mt) {
            #pragma unroll
            for (int g4 = 0; g4 < 4; ++g4) {
                const int of0 = wof + mt*32 + 8*g4 + 4*h;
                const float4 bv = *reinterpret_cast<const float4*>(bias + of0);
                #pragma unroll
                for (int nt = 0; nt < 2; ++nt) {
                    const int node = nb + nt*32 + l31;
                    const f32x16 A = acc[mt*2 + nt];
                    ushort4 s;
                    s.x = f2bf(fmaxf(A[g4*4+0] + bv.x, 0.f));
                    s.y = f2bf(fmaxf(A[g4*4+1] + bv.y, 0.f));
                    s.z = f2bf(fmaxf(A[g4*4+2] + bv.z, 0.f));
                    s.w = f2bf(fmaxf(A[g4*4+3] + bv.w, 0.f));
                    const int chunk = (wof >> 3) + mt*4 + g4;
                    *reinterpret_cast<ushort4*>(&hb[swz(node, chunk) + h*4]) = s;
                }
            }
        }
    };

    // ---- layer 1 (swapped: A = w0F fragments, B = x rows, K=16) ----
    {
        short8 af[2];
        #pragma unroll
        for (int mt = 0; mt < 2; ++mt)
            af[mt] = *reinterpret_cast<const short8*>(
                w0F + ((half*2 + mt)*64 + lane)*8);
        short8 bf[2];
        #pragma unroll
        for (int nt = 0; nt < 2; ++nt) {
            const float4 xv = *reinterpret_cast<const float4*>(
                x + (size_t)(n0 + nb + nt*32 + l31) * 4);
            short8 v = (short8){0,0,0,0,0,0,0,0};
            if (h == 0) {
                v[0] = (short)f2bf(xv.x); v[1] = (short)f2bf(xv.y);
                v[2] = (short)f2bf(xv.z); v[3] = (short)f2bf(xv.w);
            }
            bf[nt] = v;
        }
        #pragma unroll
        for (int t = 0; t < 4; ++t) acc[t] = (f32x16){};
        #pragma unroll
        for (int mt = 0; mt < 2; ++mt)
            #pragma unroll
            for (int nt = 0; nt < 2; ++nt)
                acc[mt*2 + nt] = __builtin_amdgcn_mfma_f32_32x32x16_bf16(
                    af[mt], bf[nt], acc[mt*2 + nt], 0, 0, 0);
    }
    writeback(b0);
    __syncthreads();   // all quadrants of hb visible

    // ---- layer 2 (swapped: A = w1F fragments (of-half), B = hb rows, K=128) ----
    #pragma unroll
    for (int t = 0; t < 4; ++t) acc[t] = (f32x16){};
    #pragma unroll
    for (int ks = 0; ks < 8; ++ks) {
        short8 a[2], b[2];
        #pragma unroll
        for (int mt = 0; mt < 2; ++mt)
            a[mt] = *reinterpret_cast<const short8*>(
                w1F + (((half*8 + ks)*2 + mt)*64 + lane)*8);
        #pragma unroll
        for (int nt = 0; nt < 2; ++nt)
            b[nt] = *reinterpret_cast<const short8*>(
                &hb[swz(nb + nt*32 + l31, ks*2 + h)]);
        #pragma unroll
        for (int mt = 0; mt < 2; ++mt)
            #pragma unroll
            for (int nt = 0; nt < 2; ++nt)
                acc[mt*2 + nt] = __builtin_amdgcn_mfma_f32_32x32x16_bf16(
                    a[mt], b[nt], acc[mt*2 + nt], 0, 0, 0);
    }
    __syncthreads();   // all reads of hb drained
    writeback(b1);     // overwrite own quadrant
    __syncthreads();   // writes visible

    // ---- layer 3 (normal: A = hb rows (node-half, full K), B = w2F of-half) ----
    #pragma unroll
    for (int t = 0; t < 4; ++t) acc[t] = (f32x16){};
    #pragma unroll
    for (int ks = 0; ks < 8; ++ks) {
        short8 a[2], bb[2];
        #pragma unroll
        for (int mtn = 0; mtn < 2; ++mtn)
            a[mtn] = *reinterpret_cast<const short8*>(
                &hb[swz(nb + mtn*32 + l31, ks*2 + h)]);
        #pragma unroll
        for (int ntc = 0; ntc < 2; ++ntc)
            bb[ntc] = *reinterpret_cast<const short8*>(
                w2F + (((half*8 + ks)*2 + ntc)*64 + lane)*8);
        #pragma unroll
        for (int mtn = 0; mtn < 2; ++mtn)
            #pragma unroll
            for (int ntc = 0; ntc < 2; ++ntc)
                acc[mtn*2 + ntc] = __builtin_amdgcn_mfma_f32_32x32x16_bf16(
                    a[mtn], bb[ntc], acc[mtn*2 + ntc], 0, 0, 0);
    }

    // ---- epilogue: register segmented sum. C: col=of-local (l31), row=node ----
    float b2v[2];
    #pragma unroll
    for (int ntc = 0; ntc < 2; ++ntc) b2v[ntc] = b2[wof + ntc*32 + l31];

    unsigned long long rem = mask & (mask - 1);
    int s = 0;
    while (true) {
        const int e = rem ? (int)__builtin_ctzll(rem) : 64;
        const int grun = __shfl(gi, s);
        const float cnt = (float)(e - s);
        float* gdst = g + (size_t)grun * 128 + wof;
        #pragma unroll
        for (int ntc = 0; ntc < 2; ++ntc) {
            float val = 0.f;
            #pragma unroll
            for (int mtn = 0; mtn < 2; ++mtn) {
                const f32x16 A = acc[mtn*2 + ntc];
                #pragma unroll
                for (int r = 0; r < 16; ++r) {
                    const int node = mtn*32 + (r & 3) + 8*(r >> 2) + 4*h;
                    const float inc = (node >= s && node < e) ? 1.f : 0.f;
                    val = fmaf(A[r], inc, val);
                }
            }
            val += __shfl_xor(val, 32);
            if (h == 0)
                atomicAdd(gdst + ntc*32 + l31, fmaf(cnt, b2v[ntc], val));
        }
        if (!rem) break;
        s = e;
        rem &= rem - 1;
    }
}

// ---- F head: fused 3 layers, 4 graphs/block, 1024 blocks ----
__global__ __launch_bounds__(256) void head_kernel(
        const float* __restrict__ g,
        const float* __restrict__ fw0, const float* __restrict__ fb0,
        const float* __restrict__ fw1, const float* __restrict__ fb1,
        const float* __restrict__ fw2, const float* __restrict__ fb2,
        float* __restrict__ out) {
    __shared__ float gS[128 * GS];
    __shared__ float h1T[256 * GS];
    __shared__ float red[4][8];
    const int tid = threadIdx.x;
    const int g0  = blockIdx.x * 4;

    {
        const int gr = tid >> 6, k0 = (tid & 63) * 2;
        const float2 v = *reinterpret_cast<const float2*>(
            g + (size_t)(g0 + gr) * 128 + k0);
        gS[(k0+0)*GS + gr] = v.x;
        gS[(k0+1)*GS + gr] = v.y;
    }
    __syncthreads();

    float a1[4];
    #pragma unroll
    for (int i = 0; i < 4; ++i) a1[i] = 0.f;
    #pragma unroll 4
    for (int k = 0; k < 128; ++k) {
        const float w = fw0[k * 256 + tid];
        const f32x4 v0 = *reinterpret_cast<const f32x4*>(&gS[k*GS]);
        #pragma unroll
        for (int j = 0; j < 4; ++j)
            a1[j] = fmaf(v0[j], w, a1[j]);
    }
    {
        const float bb = fb0[tid];
        f32x4 s0;
        #pragma unroll
        for (int j = 0; j < 4; ++j)
            s0[j] = fmaxf(a1[j] + bb, 0.f);
        *reinterpret_cast<f32x4*>(&h1T[tid*GS]) = s0;
    }
    __syncthreads();

    float a2[4];
    #pragma unroll
    for (int i = 0; i < 4; ++i) a2[i] = 0.f;
    #pragma unroll 4
    for (int k = 0; k < 256; ++k) {
        const float w = fw1[k * 256 + tid];
        const f32x4 v0 = *reinterpret_cast<const f32x4*>(&h1T[k*GS]);
        #pragma unroll
        for (int j = 0; j < 4; ++j)
            a2[j] = fmaf(v0[j], w, a2[j]);
    }

    float p[8];
    {
        const float bb  = fb1[tid];
        const float w2a = fw2[tid*2 + 0];
        const float w2b = fw2[tid*2 + 1];
        #pragma unroll
        for (int i = 0; i < 4; ++i) {
            const float h2 = fmaxf(a2[i] + bb, 0.f);
            p[i*2 + 0] = h2 * w2a;
            p[i*2 + 1] = h2 * w2b;
        }
    }
    #pragma unroll
    for (int i = 0; i < 8; ++i) {
        float v = p[i];
        v += __shfl_xor(v, 32); v += __shfl_xor(v, 16); v += __shfl_xor(v, 8);
        v += __shfl_xor(v, 4);  v += __shfl_xor(v, 2);  v += __shfl_xor(v, 1);
        p[i] = v;
    }
    if ((tid & 63) == 0) {
        #pragma unroll
        for (int i = 0; i < 8; ++i) red[tid >> 6][i] = p[i];
    }
    __syncthreads();
    if (tid < 8)
        out[g0*2 + tid] = red[0][tid] + red[1][tid] + red[2][tid] + red[3][tid]
                        + fb2[tid & 1];
}

extern "C" void kernel_launch(void* const* d_in, const int* in_sizes, int n_in,
                              void* d_out, int out_size, void* d_ws, size_t ws_size,
                              hipStream_t stream) {
    const float* x   = (const float*)d_in[0];
    // d_in[1] edge_index: mathematically dead (update() ignores aggr_out) — never read
    const int*   batch = (const int*)d_in[2];
    const float* w0  = (const float*)d_in[3];
    const float* b0  = (const float*)d_in[4];
    const float* w1  = (const float*)d_in[5];
    const float* b1  = (const float*)d_in[6];
    const float* w2  = (const float*)d_in[7];
    const float* b2  = (const float*)d_in[8];
    const float* fw0 = (const float*)d_in[9];
    const float* fb0 = (const float*)d_in[10];
    const float* fw1 = (const float*)d_in[11];
    const float* fb1 = (const float*)d_in[12];
    const float* fw2 = (const float*)d_in[13];
    const float* fb2 = (const float*)d_in[14];
    float* out = (float*)d_out;

    float* g = (float*)d_ws;                                        // 2 MB
    unsigned short* w1F = (unsigned short*)((char*)d_ws + (size_t)NGRAPHS * 128 * 4);
    unsigned short* w2F = w1F + 128 * 128;
    unsigned short* w0F = w2F + 128 * 128;                          // 4 KB

    (void)hipMemsetAsync(g, 0, (size_t)NGRAPHS * 128 * sizeof(float), stream);
    prep_weights<<<136, 256, 0, stream>>>(w0, w1, w2, w0F, w1F, w2F);
    phi_kernel<<<NNODES / 128, 256, 0, stream>>>(x, batch, w0F, b0, w1F, b1, w2F, b2, g);
    head_kernel<<<NGRAPHS / 4, 256, 0, stream>>>(g, fw0, fb0, fw1, fb1, fw2, fb2, out);
}

// Round 3
// 179.012 us; speedup vs baseline: 1.1902x; 1.0093x over previous
//
#include <hip/hip_runtime.h>
#include <hip/hip_bf16.h>

#define NNODES   524288
#define NGRAPHS  4096
#define GS       12    // head LDS row stride (floats)

typedef __attribute__((ext_vector_type(8)))  short short8;
typedef __attribute__((ext_vector_type(4)))  float f32x4;
typedef __attribute__((ext_vector_type(16))) float f32x16;

static __device__ __forceinline__ unsigned short f2bf(float f) {
    __hip_bfloat16 h = __float2bfloat16(f);
    return *reinterpret_cast<unsigned short*>(&h);
}

// swizzled LDS offset (shorts): node-row 128 shorts, 16B chunks XOR-permuted
static __device__ __forceinline__ int swz(int node, int chunk) {
    return node * 128 + ((chunk ^ (node & 15)) << 3);
}

// ---- one-time: zero g (float4) + weights into QUARTER-major bf16 fragment layout ----
// wF flat index = ((q*8 + ks)*64 + lane)*8 + j
//   of = q*32 + (lane&31),  k = ks*16 + (lane>>5)*8 + j
// each wave's per-ks fragment load is one contiguous 1KB (64 lanes x 16B).
__global__ __launch_bounds__(256) void prep_weights(
        const float* __restrict__ w0, const float* __restrict__ w1,
        const float* __restrict__ w2,
        unsigned short* __restrict__ w0F, unsigned short* __restrict__ w1F,
        unsigned short* __restrict__ w2F, float* __restrict__ g) {
    const int e = blockIdx.x * 256 + threadIdx.x;           // grid 512 -> e < 131072
    reinterpret_cast<float4*>(g)[e] = make_float4(0.f, 0.f, 0.f, 0.f);
    if (e < 16384) {
        const int j = e & 7, lane = (e >> 3) & 63, ks = (e >> 9) & 7, q = (e >> 12) & 3;
        const int of = q * 32 + (lane & 31);
        const int k  = ks * 16 + (lane >> 5) * 8 + j;
        w1F[e] = f2bf(w1[k * 128 + of]);
    } else if (e < 32768) {
        const int i = e - 16384;
        const int j = i & 7, lane = (i >> 3) & 63, ks = (i >> 9) & 7, q = (i >> 12) & 3;
        const int of = q * 32 + (lane & 31);
        const int k  = ks * 16 + (lane >> 5) * 8 + j;
        w2F[i] = f2bf(w2[k * 128 + of]);
    } else if (e < 34816) {
        const int i = e - 32768;           // w0F[q][lane][8], K=4 zero-padded to 16
        const int j = i & 7, lane = (i >> 3) & 63, q = (i >> 9) & 3;
        const int of = q * 32 + (lane & 31);
        const int k  = (lane >> 5) * 8 + j;
        w0F[i] = (k < 4) ? f2bf(w0[k * 128 + of]) : (unsigned short)0;
    }
}

// ---- fused phi MLP: 4 waves/block = 4 of-QUARTERS, 64 nodes/block ----
// acc = 2 tiles (32 AGPR)/wave -> 4 waves/SIMD; double-buffered hb -> 2 barriers.
__global__ __launch_bounds__(256, 4) void phi_kernel(
        const float* __restrict__ x, const int* __restrict__ batch,
        const unsigned short* __restrict__ w0F, const float* __restrict__ b0,
        const unsigned short* __restrict__ w1F, const float* __restrict__ b1,
        const unsigned short* __restrict__ w2F, const float* __restrict__ b2,
        float* __restrict__ g) {
    __shared__ __align__(16) unsigned short hb[2 * 64 * 128];   // 32 KB double-buffer
    unsigned short* const h1 = hb;
    unsigned short* const h2 = hb + 64 * 128;
    const int tid  = threadIdx.x;
    const int lane = tid & 63;
    const int q    = tid >> 6;        // of-quarter owner: of in [q*32, q*32+32)
    const int n0   = blockIdx.x * 64;
    const int l31  = lane & 31;
    const int h    = lane >> 5;

    // graph ids + run-start mask (identical in all 4 waves)
    const int gi = batch[n0 + lane];
    const int gp = __shfl_up(gi, 1);
    const unsigned long long mask = __ballot((lane == 0) || (gi != gp));

    f32x16 acc[2];

    // swapped-C writeback: col=node (lane&31), row=of-local ((reg&3)+8*(reg>>2)+4*h)
    // wave writes its of-quarter chunks [q*4, q*4+4) of all 64 node rows
    auto writeback = [&](const float* __restrict__ bias, unsigned short* __restrict__ dst) {
        #pragma unroll
        for (int g4 = 0; g4 < 4; ++g4) {
            const int of0 = q*32 + 8*g4 + 4*h;
            const float4 bv = *reinterpret_cast<const float4*>(bias + of0);
            #pragma unroll
            for (int nt = 0; nt < 2; ++nt) {
                const int node = nt*32 + l31;
                const f32x16 A = acc[nt];
                ushort4 s;
                s.x = f2bf(fmaxf(A[g4*4+0] + bv.x, 0.f));
                s.y = f2bf(fmaxf(A[g4*4+1] + bv.y, 0.f));
                s.z = f2bf(fmaxf(A[g4*4+2] + bv.z, 0.f));
                s.w = f2bf(fmaxf(A[g4*4+3] + bv.w, 0.f));
                *reinterpret_cast<ushort4*>(&dst[swz(node, q*4 + g4) + h*4]) = s;
            }
        }
    };

    // ---- layer 1 (swapped: A = w0F quarter fragment, B = x rows, K=16) ----
    {
        const short8 af = *reinterpret_cast<const short8*>(w0F + (q*64 + lane)*8);
        short8 bf[2];
        #pragma unroll
        for (int nt = 0; nt < 2; ++nt) {
            const float4 xv = *reinterpret_cast<const float4*>(
                x + (size_t)(n0 + nt*32 + l31) * 4);
            short8 v = (short8){0,0,0,0,0,0,0,0};
            if (h == 0) {
                v[0] = (short)f2bf(xv.x); v[1] = (short)f2bf(xv.y);
                v[2] = (short)f2bf(xv.z); v[3] = (short)f2bf(xv.w);
            }
            bf[nt] = v;
        }
        acc[0] = (f32x16){}; acc[1] = (f32x16){};
        #pragma unroll
        for (int nt = 0; nt < 2; ++nt)
            acc[nt] = __builtin_amdgcn_mfma_f32_32x32x16_bf16(
                af, bf[nt], acc[nt], 0, 0, 0);
    }
    writeback(b0, h1);
    __syncthreads();   // all quarters of h1 visible

    // ---- layer 2 (swapped: A = w1F quarter fragments, B = h1 rows, K=128) ----
    acc[0] = (f32x16){}; acc[1] = (f32x16){};
    #pragma unroll
    for (int ks = 0; ks < 8; ++ks) {
        const short8 a = *reinterpret_cast<const short8*>(
            w1F + ((q*8 + ks)*64 + lane)*8);
        short8 b[2];
        #pragma unroll
        for (int nt = 0; nt < 2; ++nt)
            b[nt] = *reinterpret_cast<const short8*>(
                &h1[swz(nt*32 + l31, ks*2 + h)]);
        #pragma unroll
        for (int nt = 0; nt < 2; ++nt)
            acc[nt] = __builtin_amdgcn_mfma_f32_32x32x16_bf16(
                a, b[nt], acc[nt], 0, 0, 0);
    }
    writeback(b1, h2);   // different buffer: no read-drain barrier needed
    __syncthreads();     // h2 writes visible

    // ---- layer 3 (normal: A = h2 node rows (full K), B = w2F quarter) ----
    acc[0] = (f32x16){}; acc[1] = (f32x16){};
    #pragma unroll
    for (int ks = 0; ks < 8; ++ks) {
        short8 a[2];
        #pragma unroll
        for (int mtn = 0; mtn < 2; ++mtn)
            a[mtn] = *reinterpret_cast<const short8*>(
                &h2[swz(mtn*32 + l31, ks*2 + h)]);
        const short8 bb = *reinterpret_cast<const short8*>(
            w2F + ((q*8 + ks)*64 + lane)*8);
        #pragma unroll
        for (int mtn = 0; mtn < 2; ++mtn)
            acc[mtn] = __builtin_amdgcn_mfma_f32_32x32x16_bf16(
                a[mtn], bb, acc[mtn], 0, 0, 0);
    }

    // ---- epilogue: register segmented sum. C: col=of-local (l31), row=node ----
    const float b2v = b2[q*32 + l31];

    if (mask == 1ull) {
        // whole 64-node window is one graph: unconditional sum
        float val = 0.f;
        #pragma unroll
        for (int mtn = 0; mtn < 2; ++mtn) {
            const f32x16 A = acc[mtn];
            #pragma unroll
            for (int r = 0; r < 16; ++r) val += A[r];
        }
        val += __shfl_xor(val, 32);
        if (h == 0)
            atomicAdd(g + (size_t)gi * 128 + q*32 + l31, fmaf(64.f, b2v, val));
    } else {
        unsigned long long rem = mask & (mask - 1);
        int s = 0;
        while (true) {
            const int e = rem ? (int)__builtin_ctzll(rem) : 64;
            const int grun = __shfl(gi, s);
            const float cnt = (float)(e - s);
            float val = 0.f;
            #pragma unroll
            for (int mtn = 0; mtn < 2; ++mtn) {
                const f32x16 A = acc[mtn];
                #pragma unroll
                for (int r = 0; r < 16; ++r) {
                    const int node = mtn*32 + (r & 3) + 8*(r >> 2) + 4*h;
                    const float inc = (node >= s && node < e) ? 1.f : 0.f;
                    val = fmaf(A[r], inc, val);
                }
            }
            val += __shfl_xor(val, 32);
            if (h == 0)
                atomicAdd(g + (size_t)grun * 128 + q*32 + l31, fmaf(cnt, b2v, val));
            if (!rem) break;
            s = e;
            rem &= rem - 1;
        }
    }
}

// ---- F head: fused 3 layers, 4 graphs/block, 1024 blocks ----
__global__ __launch_bounds__(256) void head_kernel(
        const float* __restrict__ g,
        const float* __restrict__ fw0, const float* __restrict__ fb0,
        const float* __restrict__ fw1, const float* __restrict__ fb1,
        const float* __restrict__ fw2, const float* __restrict__ fb2,
        float* __restrict__ out) {
    __shared__ float gS[128 * GS];
    __shared__ float h1T[256 * GS];
    __shared__ float red[4][8];
    const int tid = threadIdx.x;
    const int g0  = blockIdx.x * 4;

    {
        const int gr = tid >> 6, k0 = (tid & 63) * 2;
        const float2 v = *reinterpret_cast<const float2*>(
            g + (size_t)(g0 + gr) * 128 + k0);
        gS[(k0+0)*GS + gr] = v.x;
        gS[(k0+1)*GS + gr] = v.y;
    }
    __syncthreads();

    float a1[4];
    #pragma unroll
    for (int i = 0; i < 4; ++i) a1[i] = 0.f;
    #pragma unroll 4
    for (int k = 0; k < 128; ++k) {
        const float w = fw0[k * 256 + tid];
        const f32x4 v0 = *reinterpret_cast<const f32x4*>(&gS[k*GS]);
        #pragma unroll
        for (int j = 0; j < 4; ++j)
            a1[j] = fmaf(v0[j], w, a1[j]);
    }
    {
        const float bb = fb0[tid];
        f32x4 s0;
        #pragma unroll
        for (int j = 0; j < 4; ++j)
            s0[j] = fmaxf(a1[j] + bb, 0.f);
        *reinterpret_cast<f32x4*>(&h1T[tid*GS]) = s0;
    }
    __syncthreads();

    float a2[4];
    #pragma unroll
    for (int i = 0; i < 4; ++i) a2[i] = 0.f;
    #pragma unroll 4
    for (int k = 0; k < 256; ++k) {
        const float w = fw1[k * 256 + tid];
        const f32x4 v0 = *reinterpret_cast<const f32x4*>(&h1T[k*GS]);
        #pragma unroll
        for (int j = 0; j < 4; ++j)
            a2[j] = fmaf(v0[j], w, a2[j]);
    }

    float p[8];
    {
        const float bb  = fb1[tid];
        const float w2a = fw2[tid*2 + 0];
        const float w2b = fw2[tid*2 + 1];
        #pragma unroll
        for (int i = 0; i < 4; ++i) {
            const float h2 = fmaxf(a2[i] + bb, 0.f);
            p[i*2 + 0] = h2 * w2a;
            p[i*2 + 1] = h2 * w2b;
        }
    }
    #pragma unroll
    for (int i = 0; i < 8; ++i) {
        float v = p[i];
        v += __shfl_xor(v, 32); v += __shfl_xor(v, 16); v += __shfl_xor(v, 8);
        v += __shfl_xor(v, 4);  v += __shfl_xor(v, 2);  v += __shfl_xor(v, 1);
        p[i] = v;
    }
    if ((tid & 63) == 0) {
        #pragma unroll
        for (int i = 0; i < 8; ++i) red[tid >> 6][i] = p[i];
    }
    __syncthreads();
    if (tid < 8)
        out[g0*2 + tid] = red[0][tid] + red[1][tid] + red[2][tid] + red[3][tid]
                        + fb2[tid & 1];
}

extern "C" void kernel_launch(void* const* d_in, const int* in_sizes, int n_in,
                              void* d_out, int out_size, void* d_ws, size_t ws_size,
                              hipStream_t stream) {
    const float* x   = (const float*)d_in[0];
    // d_in[1] edge_index: mathematically dead (update() ignores aggr_out) — never read
    const int*   batch = (const int*)d_in[2];
    const float* w0  = (const float*)d_in[3];
    const float* b0  = (const float*)d_in[4];
    const float* w1  = (const float*)d_in[5];
    const float* b1  = (const float*)d_in[6];
    const float* w2  = (const float*)d_in[7];
    const float* b2  = (const float*)d_in[8];
    const float* fw0 = (const float*)d_in[9];
    const float* fb0 = (const float*)d_in[10];
    const float* fw1 = (const float*)d_in[11];
    const float* fb1 = (const float*)d_in[12];
    const float* fw2 = (const float*)d_in[13];
    const float* fb2 = (const float*)d_in[14];
    float* out = (float*)d_out;

    float* g = (float*)d_ws;                                        // 2 MB
    unsigned short* w1F = (unsigned short*)((char*)d_ws + (size_t)NGRAPHS * 128 * 4);
    unsigned short* w2F = w1F + 128 * 128;
    unsigned short* w0F = w2F + 128 * 128;                          // 4 KB

    // prep also zeroes g (grid 512*256 = 131072 float4 = 2 MB) -> no memset dispatch
    prep_weights<<<512, 256, 0, stream>>>(w0, w1, w2, w0F, w1F, w2F, g);
    phi_kernel<<<NNODES / 64, 256, 0, stream>>>(x, batch, w0F, b0, w1F, b1, w2F, b2, g);
    head_kernel<<<NGRAPHS / 4, 256, 0, stream>>>(g, fw0, fb0, fw1, fb1, fw2, fb2, out);
}

// Round 5
// 168.815 us; speedup vs baseline: 1.2620x; 1.0604x over previous
//
#include <hip/hip_runtime.h>
#include <hip/hip_bf16.h>

#define NNODES   524288
#define NGRAPHS  4096
#define GS       12    // head LDS row stride (floats)

typedef __attribute__((ext_vector_type(8)))  short short8;
typedef __attribute__((ext_vector_type(4)))  float f32x4;
typedef __attribute__((ext_vector_type(16))) float f32x16;

static __device__ __forceinline__ unsigned short f2bf(float f) {
    __hip_bfloat16 h = __float2bfloat16(f);
    return *reinterpret_cast<unsigned short*>(&h);
}

// swizzled LDS offset (shorts): node-row 128 shorts, 16B chunks XOR-permuted
static __device__ __forceinline__ int swz(int node, int chunk) {
    return node * 128 + ((chunk ^ (node & 15)) << 3);
}

// ---- one-time prep ----
// zeroes P+cnts (2MB+16KB), builds w1F/w0F bf16 fragment layouts, and
// folds phi layer-3 into the head: W0p = w2 @ fw0 (128x256), c0p = b2 @ fw0.
__global__ __launch_bounds__(256) void prep_weights(
        const float* __restrict__ w0, const float* __restrict__ w1,
        const float* __restrict__ w2, const float* __restrict__ fw0,
        const float* __restrict__ b2,
        unsigned short* __restrict__ w0F, unsigned short* __restrict__ w1F,
        float* __restrict__ W0p, float* __restrict__ c0p,
        float* __restrict__ Pz) {
    const int e = blockIdx.x * 256 + threadIdx.x;       // grid 516 -> e < 132096
    if (e < 132096)                                     // P (2MB) + cnts (16KB)
        reinterpret_cast<float4*>(Pz)[e] = make_float4(0.f, 0.f, 0.f, 0.f);
    if (e < 16384) {
        // w1F: of = q*32+(lane&31), k = ks*16+(lane>>5)*8+j  (A- and B-role compatible)
        const int j = e & 7, lane = (e >> 3) & 63, ks = (e >> 9) & 7, q = (e >> 12) & 3;
        const int of = q * 32 + (lane & 31);
        const int k  = ks * 16 + (lane >> 5) * 8 + j;
        w1F[e] = f2bf(w1[k * 128 + of]);
    } else if (e < 18432) {
        const int i = e - 16384;           // w0F[q][lane][8], K=4 zero-padded to 16
        const int j = i & 7, lane = (i >> 3) & 63, q = (i >> 9) & 3;
        const int of = q * 32 + (lane & 31);
        const int k  = (lane >> 5) * 8 + j;
        w0F[i] = (k < 4) ? f2bf(w0[k * 128 + of]) : (unsigned short)0;
    } else if (e < 51200) {
        const int i = e - 18432;           // W0p[kp][o] = sum_of w2[kp][of]*fw0[of][o]
        const int o = i & 255, kp = i >> 8;
        float v = 0.f;
        #pragma unroll 8
        for (int of = 0; of < 128; ++of)
            v = fmaf(w2[kp * 128 + of], fw0[of * 256 + o], v);
        W0p[kp * 256 + o] = v;
    } else if (e < 51456) {
        const int o = e - 51200;           // c0p[o] = sum_of b2[of]*fw0[of][o]
        float v = 0.f;
        #pragma unroll 8
        for (int of = 0; of < 128; ++of)
            v = fmaf(b2[of], fw0[of * 256 + o], v);
        c0p[o] = v;
    }
}

// ---- fused phi MLP (2 layers) + f32 segmented pooling ----
// 4 waves/block = 4 of-quarters, 64 nodes/block. Layer 3 folded into head.
__global__ __launch_bounds__(256, 6) void phi_kernel(
        const float* __restrict__ x, const int* __restrict__ batch,
        const unsigned short* __restrict__ w0F, const float* __restrict__ b0,
        const unsigned short* __restrict__ w1F, const float* __restrict__ b1,
        float* __restrict__ P, float* __restrict__ cnts) {
    __shared__ __align__(16) unsigned short h1[64 * 128];   // 16 KB
    const int tid  = threadIdx.x;
    const int lane = tid & 63;
    const int q    = tid >> 6;        // of-quarter owner: of in [q*32, q*32+32)
    const int n0   = blockIdx.x * 64;
    const int l31  = lane & 31;
    const int h    = lane >> 5;

    // graph ids + run-start mask (identical in all 4 waves)
    const int gi = batch[n0 + lane];
    const int gp = __shfl_up(gi, 1);
    const unsigned long long mask = __ballot((lane == 0) || (gi != gp));

    f32x16 acc[2];

    // ---- layer 1 (swapped: A = w0F quarter fragment, B = x rows, K=16) ----
    {
        const short8 af = *reinterpret_cast<const short8*>(w0F + (q*64 + lane)*8);
        short8 bf[2];
        #pragma unroll
        for (int nt = 0; nt < 2; ++nt) {
            const float4 xv = *reinterpret_cast<const float4*>(
                x + (size_t)(n0 + nt*32 + l31) * 4);
            short8 v = (short8){0,0,0,0,0,0,0,0};
            if (h == 0) {
                v[0] = (short)f2bf(xv.x); v[1] = (short)f2bf(xv.y);
                v[2] = (short)f2bf(xv.z); v[3] = (short)f2bf(xv.w);
            }
            bf[nt] = v;
        }
        acc[0] = (f32x16){}; acc[1] = (f32x16){};
        #pragma unroll
        for (int nt = 0; nt < 2; ++nt)
            acc[nt] = __builtin_amdgcn_mfma_f32_32x32x16_bf16(
                af, bf[nt], acc[nt], 0, 0, 0);
    }
    // ---- writeback h1: bias b0 + ReLU + bf16 (C: col=node(l31), row=of-local) ----
    #pragma unroll
    for (int g4 = 0; g4 < 4; ++g4) {
        const int of0 = q*32 + 8*g4 + 4*h;
        const float4 bv = *reinterpret_cast<const float4*>(b0 + of0);
        #pragma unroll
        for (int nt = 0; nt < 2; ++nt) {
            const int node = nt*32 + l31;
            const f32x16 A = acc[nt];
            ushort4 s;
            s.x = f2bf(fmaxf(A[g4*4+0] + bv.x, 0.f));
            s.y = f2bf(fmaxf(A[g4*4+1] + bv.y, 0.f));
            s.z = f2bf(fmaxf(A[g4*4+2] + bv.z, 0.f));
            s.w = f2bf(fmaxf(A[g4*4+3] + bv.w, 0.f));
            *reinterpret_cast<ushort4*>(&h1[swz(node, q*4 + g4) + h*4]) = s;
        }
    }
    __syncthreads();   // all quarters of h1 visible

    // ---- layer 2 (NORMAL: A = h1 node rows (full K=128), B = w1F of-quarter) ----
    // C: col=of-local(l31), row=node -> pooling is register-local per lane.
    acc[0] = (f32x16){}; acc[1] = (f32x16){};
    #pragma unroll
    for (int ks = 0; ks < 8; ++ks) {
        short8 a[2];
        #pragma unroll
        for (int mtn = 0; mtn < 2; ++mtn)
            a[mtn] = *reinterpret_cast<const short8*>(
                &h1[swz(mtn*32 + l31, ks*2 + h)]);
        const short8 bb = *reinterpret_cast<const short8*>(
            w1F + ((q*8 + ks)*64 + lane)*8);
        #pragma unroll
        for (int mtn = 0; mtn < 2; ++mtn)
            acc[mtn] = __builtin_amdgcn_mfma_f32_32x32x16_bf16(
                a[mtn], bb, acc[mtn], 0, 0, 0);
    }

    // ---- bias b1 + ReLU in f32 (of = q*32+l31 fixed per lane) ----
    const float b1v = b1[q*32 + l31];
    #pragma unroll
    for (int mtn = 0; mtn < 2; ++mtn)
        #pragma unroll
        for (int r = 0; r < 16; ++r)
            acc[mtn][r] = fmaxf(acc[mtn][r] + b1v, 0.f);

    // ---- pooled segmented sum -> P[graph][of], plus node counts ----
    if (mask == 1ull) {
        float val = 0.f;
        #pragma unroll
        for (int mtn = 0; mtn < 2; ++mtn) {
            const f32x16 A = acc[mtn];
            #pragma unroll
            for (int r = 0; r < 16; ++r) val += A[r];
        }
        val += __shfl_xor(val, 32);
        if (h == 0)
            atomicAdd(P + (size_t)gi * 128 + q*32 + l31, val);
        if (tid == 0)
            atomicAdd(cnts + gi, 64.f);
    } else {
        unsigned long long rem = mask & (mask - 1);
        int s = 0;
        while (true) {
            const int e = rem ? (int)__builtin_ctzll(rem) : 64;
            const int grun = __shfl(gi, s);
            float val = 0.f;
            #pragma unroll
            for (int mtn = 0; mtn < 2; ++mtn) {
                const f32x16 A = acc[mtn];
                #pragma unroll
                for (int r = 0; r < 16; ++r) {
                    const int node = mtn*32 + (r & 3) + 8*(r >> 2) + 4*h;
                    const float inc = (node >= s && node < e) ? 1.f : 0.f;
                    val = fmaf(A[r], inc, val);
                }
            }
            val += __shfl_xor(val, 32);
            if (h == 0)
                atomicAdd(P + (size_t)grun * 128 + q*32 + l31, val);
            if (tid == 0)
                atomicAdd(cnts + grun, (float)(e - s));
            if (!rem) break;
            s = e;
            rem &= rem - 1;
        }
    }
}

// ---- F head: a1 = P@W0p + cnt*c0p + fb0 (folded phi-L3), then fw1, fw2 ----
__global__ __launch_bounds__(256) void head_kernel(
        const float* __restrict__ P, const float* __restrict__ cnts,
        const float* __restrict__ W0p, const float* __restrict__ c0p,
        const float* __restrict__ fb0,
        const float* __restrict__ fw1, const float* __restrict__ fb1,
        const float* __restrict__ fw2, const float* __restrict__ fb2,
        float* __restrict__ out) {
    __shared__ float gS[128 * GS];
    __shared__ float h1T[256 * GS];
    __shared__ float red[4][8];
    __shared__ float cntS[4];
    const int tid = threadIdx.x;
    const int g0  = blockIdx.x * 4;

    if (tid < 4) cntS[tid] = cnts[g0 + tid];
    {
        const int gr = tid >> 6, k0 = (tid & 63) * 2;
        const float2 v = *reinterpret_cast<const float2*>(
            P + (size_t)(g0 + gr) * 128 + k0);
        gS[(k0+0)*GS + gr] = v.x;
        gS[(k0+1)*GS + gr] = v.y;
    }
    __syncthreads();

    float a1[4];
    #pragma unroll
    for (int i = 0; i < 4; ++i) a1[i] = 0.f;
    #pragma unroll 4
    for (int k = 0; k < 128; ++k) {
        const float w = W0p[k * 256 + tid];
        const f32x4 v0 = *reinterpret_cast<const f32x4*>(&gS[k*GS]);
        #pragma unroll
        for (int j = 0; j < 4; ++j)
            a1[j] = fmaf(v0[j], w, a1[j]);
    }
    {
        const float bb = fb0[tid];
        const float cc = c0p[tid];
        f32x4 s0;
        #pragma unroll
        for (int j = 0; j < 4; ++j)
            s0[j] = fmaxf(fmaf(cntS[j], cc, a1[j]) + bb, 0.f);
        *reinterpret_cast<f32x4*>(&h1T[tid*GS]) = s0;
    }
    __syncthreads();

    float a2[4];
    #pragma unroll
    for (int i = 0; i < 4; ++i) a2[i] = 0.f;
    #pragma unroll 4
    for (int k = 0; k < 256; ++k) {
        const float w = fw1[k * 256 + tid];
        const f32x4 v0 = *reinterpret_cast<const f32x4*>(&h1T[k*GS]);
        #pragma unroll
        for (int j = 0; j < 4; ++j)
            a2[j] = fmaf(v0[j], w, a2[j]);
    }

    float p[8];
    {
        const float bb  = fb1[tid];
        const float w2a = fw2[tid*2 + 0];
        const float w2b = fw2[tid*2 + 1];
        #pragma unroll
        for (int i = 0; i < 4; ++i) {
            const float h2 = fmaxf(a2[i] + bb, 0.f);
            p[i*2 + 0] = h2 * w2a;
            p[i*2 + 1] = h2 * w2b;
        }
    }
    #pragma unroll
    for (int i = 0; i < 8; ++i) {
        float v = p[i];
        v += __shfl_xor(v, 32); v += __shfl_xor(v, 16); v += __shfl_xor(v, 8);
        v += __shfl_xor(v, 4);  v += __shfl_xor(v, 2);  v += __shfl_xor(v, 1);
        p[i] = v;
    }
    if ((tid & 63) == 0) {
        #pragma unroll
        for (int i = 0; i < 8; ++i) red[tid >> 6][i] = p[i];
    }
    __syncthreads();
    if (tid < 8)
        out[g0*2 + tid] = red[0][tid] + red[1][tid] + red[2][tid] + red[3][tid]
                        + fb2[tid & 1];
}

extern "C" void kernel_launch(void* const* d_in, const int* in_sizes, int n_in,
                              void* d_out, int out_size, void* d_ws, size_t ws_size,
                              hipStream_t stream) {
    const float* x   = (const float*)d_in[0];
    // d_in[1] edge_index: mathematically dead (update() ignores aggr_out) — never read
    const int*   batch = (const int*)d_in[2];
    const float* w0  = (const float*)d_in[3];
    const float* b0  = (const float*)d_in[4];
    const float* w1  = (const float*)d_in[5];
    const float* b1  = (const float*)d_in[6];
    const float* w2  = (const float*)d_in[7];
    const float* b2  = (const float*)d_in[8];
    const float* fw0 = (const float*)d_in[9];
    const float* fb0 = (const float*)d_in[10];
    const float* fw1 = (const float*)d_in[11];
    const float* fb1 = (const float*)d_in[12];
    const float* fw2 = (const float*)d_in[13];
    const float* fb2 = (const float*)d_in[14];
    float* out = (float*)d_out;

    float* P    = (float*)d_ws;                       // 4096*128 f32 = 2 MB
    float* cnts = P + (size_t)NGRAPHS * 128;          // 4096 f32 = 16 KB
    unsigned short* w1F = (unsigned short*)(cnts + NGRAPHS);   // 32 KB
    unsigned short* w0F = w1F + 16384;                // 4 KB
    float* W0p = (float*)(w0F + 2048);                // 128*256 f32 = 128 KB
    float* c0p = W0p + 128 * 256;                     // 1 KB

    // prep zeroes P+cnts (516*256 = 132096 float4) and builds all weight forms
    prep_weights<<<516, 256, 0, stream>>>(w0, w1, w2, fw0, b2, w0F, w1F, W0p, c0p, P);
    phi_kernel<<<NNODES / 64, 256, 0, stream>>>(x, batch, w0F, b0, w1F, b1, P, cnts);
    head_kernel<<<NGRAPHS / 4, 256, 0, stream>>>(P, cnts, W0p, c0p, fb0,
                                                 fw1, fb1, fw2, fb2, out);
}